// Round 1
// baseline (602.334 us; speedup 1.0000x reference)
//
#include <hip/hip_runtime.h>

#define NN 100000      // nodes
#define NE 1600000     // edges
#define INF 32
#define HF 32
#define CF 8

// ---------------- degree counts ----------------
__global__ void deg_kernel(const int* __restrict__ src, const int* __restrict__ dst,
                           float* __restrict__ deg_out, float* __restrict__ deg_in) {
    int e = blockIdx.x * blockDim.x + threadIdx.x;
    if (e < NE) {
        atomicAdd(&deg_out[src[e]], 1.0f);
        atomicAdd(&deg_in[dst[e]], 1.0f);
    }
}

// ---------------- h = (x @ W1) * rsqrt(deg_out) ----------------
__global__ void xw1_kernel(const float* __restrict__ x, const float* __restrict__ W1,
                           const float* __restrict__ deg_out, float* __restrict__ h) {
    __shared__ float w[INF * HF];
    for (int i = threadIdx.x; i < INF * HF; i += blockDim.x) w[i] = W1[i];
    __syncthreads();
    int n = blockIdx.x * blockDim.x + threadIdx.x;
    if (n >= NN) return;

    float xr[INF];
    const float4* xp = (const float4*)(x + (size_t)n * INF);
    #pragma unroll
    for (int i = 0; i < INF / 4; ++i) {
        float4 v = xp[i];
        xr[4*i+0] = v.x; xr[4*i+1] = v.y; xr[4*i+2] = v.z; xr[4*i+3] = v.w;
    }
    float acc[HF];
    #pragma unroll
    for (int c = 0; c < HF; ++c) acc[c] = 0.0f;
    #pragma unroll
    for (int k = 0; k < INF; ++k) {
        float xv = xr[k];
        #pragma unroll
        for (int c = 0; c < HF; ++c) acc[c] = fmaf(xv, w[k * HF + c], acc[c]);
    }
    float rs = rsqrtf(fmaxf(deg_out[n], 1.0f));
    float4* hp = (float4*)(h + (size_t)n * HF);
    #pragma unroll
    for (int i = 0; i < HF / 4; ++i) {
        float4 v;
        v.x = acc[4*i+0] * rs; v.y = acc[4*i+1] * rs;
        v.z = acc[4*i+2] * rs; v.w = acc[4*i+3] * rs;
        hp[i] = v;
    }
}

// ---------------- agg1[dst] += h[src]  (32 lanes per edge) ----------------
__global__ void scatter1_kernel(const int* __restrict__ src, const int* __restrict__ dst,
                                const float* __restrict__ h, float* __restrict__ agg) {
    int t = blockIdx.x * blockDim.x + threadIdx.x;   // < NE*32 = 51.2M
    int e = t >> 5, f = t & 31;
    if (e < NE) {
        int s = src[e], d = dst[e];
        atomicAdd(&agg[(size_t)d * HF + f], h[(size_t)s * HF + f]);
    }
}

// ---------------- pre2 = (relu(agg1*rs_in + b1) @ W2) * rs_out ----------------
__global__ void layer2_kernel(const float* __restrict__ agg1,
                              const float* __restrict__ deg_in, const float* __restrict__ deg_out,
                              const float* __restrict__ b1, const float* __restrict__ W2,
                              float* __restrict__ pre2) {
    __shared__ float w[HF * CF];
    __shared__ float bs[HF];
    for (int i = threadIdx.x; i < HF * CF; i += blockDim.x) w[i] = W2[i];
    for (int i = threadIdx.x; i < HF; i += blockDim.x) bs[i] = b1[i];
    __syncthreads();
    int n = blockIdx.x * blockDim.x + threadIdx.x;
    if (n >= NN) return;

    float rs_in  = rsqrtf(fmaxf(deg_in[n], 1.0f));
    float rs_out = rsqrtf(fmaxf(deg_out[n], 1.0f));
    float acc[CF];
    #pragma unroll
    for (int c = 0; c < CF; ++c) acc[c] = 0.0f;
    const float4* ap = (const float4*)(agg1 + (size_t)n * HF);
    #pragma unroll
    for (int i = 0; i < HF / 4; ++i) {
        float4 v = ap[i];
        float hv[4] = {v.x, v.y, v.z, v.w};
        #pragma unroll
        for (int j = 0; j < 4; ++j) {
            int k = 4 * i + j;
            float h1 = fmaxf(fmaf(hv[j], rs_in, bs[k]), 0.0f);  // relu(agg*rs_in + b1)
            #pragma unroll
            for (int c = 0; c < CF; ++c) acc[c] = fmaf(h1, w[k * CF + c], acc[c]);
        }
    }
    float4* pp = (float4*)(pre2 + (size_t)n * CF);
    #pragma unroll
    for (int i = 0; i < CF / 4; ++i) {
        float4 v;
        v.x = acc[4*i+0] * rs_out; v.y = acc[4*i+1] * rs_out;
        v.z = acc[4*i+2] * rs_out; v.w = acc[4*i+3] * rs_out;
        pp[i] = v;
    }
}

// ---------------- agg2[dst] += pre2[src]  (8 lanes per edge) ----------------
__global__ void scatter2_kernel(const int* __restrict__ src, const int* __restrict__ dst,
                                const float* __restrict__ pre2, float* __restrict__ agg) {
    int t = blockIdx.x * blockDim.x + threadIdx.x;   // < NE*8 = 12.8M
    int e = t >> 3, f = t & 7;
    if (e < NE) {
        int s = src[e], d = dst[e];
        atomicAdd(&agg[(size_t)d * CF + f], pre2[(size_t)s * CF + f]);
    }
}

// ---------------- sum over nodes of agg2*rs_in -> acc[8] ----------------
__global__ void reduce_kernel(const float* __restrict__ agg2,
                              const float* __restrict__ deg_in, float* __restrict__ acc) {
    int n = blockIdx.x * blockDim.x + threadIdx.x;
    float v[CF];
    #pragma unroll
    for (int c = 0; c < CF; ++c) v[c] = 0.0f;
    if (n < NN) {
        float rs = rsqrtf(fmaxf(deg_in[n], 1.0f));
        const float4* ap = (const float4*)(agg2 + (size_t)n * CF);
        float4 a = ap[0], b = ap[1];
        v[0] = a.x * rs; v[1] = a.y * rs; v[2] = a.z * rs; v[3] = a.w * rs;
        v[4] = b.x * rs; v[5] = b.y * rs; v[6] = b.z * rs; v[7] = b.w * rs;
    }
    // wave-64 butterfly reduce each channel
    #pragma unroll
    for (int off = 32; off > 0; off >>= 1) {
        #pragma unroll
        for (int c = 0; c < CF; ++c) v[c] += __shfl_down(v[c], off, 64);
    }
    if ((threadIdx.x & 63) == 0) {
        #pragma unroll
        for (int c = 0; c < CF; ++c) atomicAdd(&acc[c], v[c]);
    }
}

// ---------------- out = acc/N + b2 ----------------
__global__ void finalize_kernel(const float* __restrict__ acc, const float* __restrict__ b2,
                                float* __restrict__ out) {
    int c = threadIdx.x;
    if (c < CF) out[c] = acc[c] * (1.0f / NN) + b2[c];
}

extern "C" void kernel_launch(void* const* d_in, const int* in_sizes, int n_in,
                              void* d_out, int out_size, void* d_ws, size_t ws_size,
                              hipStream_t stream) {
    const float* x   = (const float*)d_in[0];
    const int*   src = (const int*)  d_in[1];
    const int*   dst = (const int*)  d_in[2];
    const float* W1  = (const float*)d_in[3];
    const float* b1  = (const float*)d_in[4];
    const float* W2  = (const float*)d_in[5];
    const float* b2  = (const float*)d_in[6];
    float* out = (float*)d_out;

    float* ws      = (float*)d_ws;
    float* deg_out = ws;                    // [NN]
    float* deg_in  = deg_out + NN;          // [NN]
    float* h       = deg_in + NN;           // [NN*32]
    float* agg1    = h + (size_t)NN * HF;   // [NN*32]
    float* pre2    = agg1 + (size_t)NN * HF;// [NN*8]
    float* agg2    = pre2 + (size_t)NN * CF;// [NN*8]
    float* acc     = agg2 + (size_t)NN * CF;// [8]

    // zero accumulators (deterministic per call)
    hipMemsetAsync(deg_out, 0, 2 * (size_t)NN * sizeof(float), stream);
    hipMemsetAsync(agg1, 0, (size_t)NN * HF * sizeof(float), stream);
    hipMemsetAsync(agg2, 0, ((size_t)NN * CF + CF) * sizeof(float), stream);  // agg2 + acc

    const int B = 256;
    deg_kernel<<<(NE + B - 1) / B, B, 0, stream>>>(src, dst, deg_out, deg_in);
    xw1_kernel<<<(NN + B - 1) / B, B, 0, stream>>>(x, W1, deg_out, h);
    scatter1_kernel<<<((size_t)NE * 32 + B - 1) / B, B, 0, stream>>>(src, dst, h, agg1);
    layer2_kernel<<<(NN + B - 1) / B, B, 0, stream>>>(agg1, deg_in, deg_out, b1, W2, pre2);
    scatter2_kernel<<<((size_t)NE * 8 + B - 1) / B, B, 0, stream>>>(src, dst, pre2, agg2);
    reduce_kernel<<<(NN + B - 1) / B, B, 0, stream>>>(agg2, deg_in, acc);
    finalize_kernel<<<1, 64, 0, stream>>>(acc, b2, out);
}

// Round 2
// 376.616 us; speedup vs baseline: 1.5993x; 1.5993x over previous
//
#include <hip/hip_runtime.h>

#define NN 100000      // nodes
#define NE 1600000     // edges
#define INF 32
#define HF 32
#define CF 8
#define SCAN_CHUNK 1024
#define NBLK_SCAN ((NN + SCAN_CHUNK - 1) / SCAN_CHUNK)   // 98

// ---------------- K1: degree histograms (int atomics) ----------------
__global__ void deg_kernel(const int* __restrict__ src, const int* __restrict__ dst,
                           int* __restrict__ deg_out, int* __restrict__ deg_in) {
    int e = blockIdx.x * blockDim.x + threadIdx.x;
    if (e < NE) {
        atomicAdd(&deg_out[src[e]], 1);
        atomicAdd(&deg_in[dst[e]], 1);
    }
}

// ---------------- K2a: per-chunk sums of deg_in ----------------
__global__ void chunk_sum_kernel(const int* __restrict__ deg_in, int* __restrict__ bsum) {
    // 256 threads, each loads 4 coalesced
    int base = blockIdx.x * SCAN_CHUNK;
    int s = 0;
    #pragma unroll
    for (int k = 0; k < 4; ++k) {
        int i = base + threadIdx.x + k * 256;
        if (i < NN) s += deg_in[i];
    }
    // wave + LDS reduce
    #pragma unroll
    for (int off = 32; off > 0; off >>= 1) s += __shfl_down(s, off, 64);
    __shared__ int ws_[4];
    if ((threadIdx.x & 63) == 0) ws_[threadIdx.x >> 6] = s;
    __syncthreads();
    if (threadIdx.x == 0) bsum[blockIdx.x] = ws_[0] + ws_[1] + ws_[2] + ws_[3];
}

// ---------------- K2b: exclusive scan of chunk sums (1 block, 128 thr) ----------------
__global__ void chunk_scan_kernel(const int* __restrict__ bsum, int* __restrict__ boff) {
    __shared__ int tmp[128];
    int tid = threadIdx.x;
    int v = (tid < NBLK_SCAN) ? bsum[tid] : 0;
    tmp[tid] = v;
    __syncthreads();
    for (int off = 1; off < 128; off <<= 1) {
        int t = (tid >= off) ? tmp[tid - off] : 0;
        __syncthreads();
        tmp[tid] += t;
        __syncthreads();
    }
    if (tid < NBLK_SCAN) boff[tid] = tmp[tid] - v;   // exclusive
}

// ---------------- K2c: full exclusive scan -> row_ptr, cursor ----------------
__global__ void row_ptr_kernel(const int* __restrict__ deg_in, const int* __restrict__ boff,
                               int* __restrict__ row_ptr, int* __restrict__ cursor) {
    __shared__ int tmp[SCAN_CHUNK];
    int tid = threadIdx.x;
    int i = blockIdx.x * SCAN_CHUNK + tid;
    int v = (i < NN) ? deg_in[i] : 0;
    tmp[tid] = v;
    __syncthreads();
    for (int off = 1; off < SCAN_CHUNK; off <<= 1) {
        int t = (tid >= off) ? tmp[tid - off] : 0;
        __syncthreads();
        tmp[tid] += t;
        __syncthreads();
    }
    if (i < NN) {
        int excl = boff[blockIdx.x] + tmp[tid] - v;
        row_ptr[i] = excl;
        cursor[i] = excl;
        if (i == NN - 1) row_ptr[NN] = NE;
    }
}

// ---------------- K4: h = (x @ W1) * rsqrt(deg_out) ----------------
__global__ void xw1_kernel(const float* __restrict__ x, const float* __restrict__ W1,
                           const int* __restrict__ deg_out, float* __restrict__ h) {
    __shared__ float w[INF * HF];
    for (int i = threadIdx.x; i < INF * HF; i += blockDim.x) w[i] = W1[i];
    __syncthreads();
    int n = blockIdx.x * blockDim.x + threadIdx.x;
    if (n >= NN) return;

    float xr[INF];
    const float4* xp = (const float4*)(x + (size_t)n * INF);
    #pragma unroll
    for (int i = 0; i < INF / 4; ++i) {
        float4 v = xp[i];
        xr[4*i+0] = v.x; xr[4*i+1] = v.y; xr[4*i+2] = v.z; xr[4*i+3] = v.w;
    }
    float acc[HF];
    #pragma unroll
    for (int c = 0; c < HF; ++c) acc[c] = 0.0f;
    #pragma unroll
    for (int k = 0; k < INF; ++k) {
        float xv = xr[k];
        #pragma unroll
        for (int c = 0; c < HF; ++c) acc[c] = fmaf(xv, w[k * HF + c], acc[c]);
    }
    float rs = rsqrtf(fmaxf((float)deg_out[n], 1.0f));
    float4* hp = (float4*)(h + (size_t)n * HF);
    #pragma unroll
    for (int i = 0; i < HF / 4; ++i) {
        float4 v;
        v.x = acc[4*i+0] * rs; v.y = acc[4*i+1] * rs;
        v.z = acc[4*i+2] * rs; v.w = acc[4*i+3] * rs;
        hp[i] = v;
    }
}

// ---------------- K3: CSR fill + w scatter ----------------
// ebuf[row_ptr[dst]+k] = src ;  w[src] += rsqrt(deg_in[dst])
__global__ void fill_kernel(const int* __restrict__ src, const int* __restrict__ dst,
                            const int* __restrict__ deg_in,
                            int* __restrict__ cursor, int* __restrict__ ebuf,
                            float* __restrict__ w) {
    int e = blockIdx.x * blockDim.x + threadIdx.x;
    if (e < NE) {
        int d = dst[e], s = src[e];
        int pos = atomicAdd(&cursor[d], 1);
        ebuf[pos] = s;
        float riv = rsqrtf(fmaxf((float)deg_in[d], 1.0f));
        atomicAdd(&w[s], riv);
    }
}

// ---------------- K6: fused gather-aggregate + relu + weighted reduce ----------------
// per node n: agg = sum_{j} h[ebuf[j]];  relu1 = max(agg*rs_in + b1, 0)
// v[32] += (rs_out[n]*w[n]) * relu1      (global 32-vector)
__global__ void __launch_bounds__(256) gather_kernel(
        const int* __restrict__ row_ptr, const int* __restrict__ ebuf,
        const float* __restrict__ h,
        const int* __restrict__ deg_in, const int* __restrict__ deg_out,
        const float* __restrict__ w, const float* __restrict__ b1,
        float* __restrict__ v) {
    const int lane8 = threadIdx.x & 7;       // feature sub-group
    const int f0 = lane8 * 4;
    const int group = (blockIdx.x * blockDim.x + threadIdx.x) >> 3;   // global node-group
    const int ngroups = (gridDim.x * blockDim.x) >> 3;

    float b1r[4];
    #pragma unroll
    for (int c = 0; c < 4; ++c) b1r[c] = b1[f0 + c];

    float vacc[4] = {0.f, 0.f, 0.f, 0.f};

    for (int n = group; n < NN; n += ngroups) {
        int beg = row_ptr[n];
        int end = row_ptr[n + 1];
        float4 agg = {0.f, 0.f, 0.f, 0.f};
        for (int j = beg; j < end; ++j) {
            int s = ebuf[j];
            float4 hv = *(const float4*)(h + (size_t)s * HF + f0);
            agg.x += hv.x; agg.y += hv.y; agg.z += hv.z; agg.w += hv.w;
        }
        float rs_in  = rsqrtf(fmaxf((float)deg_in[n], 1.0f));
        float rs_out = rsqrtf(fmaxf((float)deg_out[n], 1.0f));
        float alpha = rs_out * w[n];
        vacc[0] += alpha * fmaxf(fmaf(agg.x, rs_in, b1r[0]), 0.f);
        vacc[1] += alpha * fmaxf(fmaf(agg.y, rs_in, b1r[1]), 0.f);
        vacc[2] += alpha * fmaxf(fmaf(agg.z, rs_in, b1r[2]), 0.f);
        vacc[3] += alpha * fmaxf(fmaf(agg.w, rs_in, b1r[3]), 0.f);
    }

    // reduce across the 8 groups within the wave (lanes differing in bits 3,4,5)
    #pragma unroll
    for (int c = 0; c < 4; ++c) {
        vacc[c] += __shfl_xor(vacc[c], 8, 64);
        vacc[c] += __shfl_xor(vacc[c], 16, 64);
        vacc[c] += __shfl_xor(vacc[c], 32, 64);
    }
    __shared__ float vl[32];
    if (threadIdx.x < 32) vl[threadIdx.x] = 0.f;
    __syncthreads();
    if ((threadIdx.x & 63) < 8) {
        #pragma unroll
        for (int c = 0; c < 4; ++c) atomicAdd(&vl[f0 + c], vacc[c]);
    }
    __syncthreads();
    if (threadIdx.x < 32) atomicAdd(&v[threadIdx.x], vl[threadIdx.x]);
}

// ---------------- K7: out = (v @ W2)/N + b2 ----------------
__global__ void final_kernel(const float* __restrict__ v, const float* __restrict__ W2,
                             const float* __restrict__ b2, float* __restrict__ out) {
    int c = threadIdx.x;
    if (c < CF) {
        float s = 0.f;
        #pragma unroll
        for (int k = 0; k < HF; ++k) s = fmaf(v[k], W2[k * CF + c], s);
        out[c] = s * (1.0f / NN) + b2[c];
    }
}

extern "C" void kernel_launch(void* const* d_in, const int* in_sizes, int n_in,
                              void* d_out, int out_size, void* d_ws, size_t ws_size,
                              hipStream_t stream) {
    const float* x   = (const float*)d_in[0];
    const int*   src = (const int*)  d_in[1];
    const int*   dst = (const int*)  d_in[2];
    const float* W1  = (const float*)d_in[3];
    const float* b1  = (const float*)d_in[4];
    const float* W2  = (const float*)d_in[5];
    const float* b2  = (const float*)d_in[6];
    float* out = (float*)d_out;

    char* ws = (char*)d_ws;
    int*   deg_out = (int*)ws;                    ws += NN * 4;
    int*   deg_in  = (int*)ws;                    ws += NN * 4;
    int*   row_ptr = (int*)ws;                    ws += (NN + 1) * 4;
    int*   cursor  = (int*)ws;                    ws += NN * 4;
    int*   bsum    = (int*)ws;                    ws += 128 * 4;
    int*   boff    = (int*)ws;                    ws += 128 * 4;
    int*   ebuf    = (int*)ws;                    ws += (size_t)NE * 4;
    float* h       = (float*)ws;                  ws += (size_t)NN * HF * 4;
    float* wgt     = (float*)ws;                  ws += NN * 4;
    float* v       = (float*)ws;                  ws += 32 * 4;

    // zero the accumulators we atomically build
    hipMemsetAsync(deg_out, 0, 2 * (size_t)NN * 4, stream);       // deg_out + deg_in
    hipMemsetAsync(wgt, 0, (NN + 32) * 4, stream);                // wgt + v (adjacent)

    const int B = 256;
    deg_kernel<<<(NE + B - 1) / B, B, 0, stream>>>(src, dst, deg_out, deg_in);
    chunk_sum_kernel<<<NBLK_SCAN, 256, 0, stream>>>(deg_in, bsum);
    chunk_scan_kernel<<<1, 128, 0, stream>>>(bsum, boff);
    row_ptr_kernel<<<NBLK_SCAN, SCAN_CHUNK, 0, stream>>>(deg_in, boff, row_ptr, cursor);
    xw1_kernel<<<(NN + B - 1) / B, B, 0, stream>>>(x, W1, deg_out, h);
    fill_kernel<<<(NE + B - 1) / B, B, 0, stream>>>(src, dst, deg_in, cursor, ebuf, wgt);
    gather_kernel<<<2048, B, 0, stream>>>(row_ptr, ebuf, h, deg_in, deg_out, wgt, b1, v);
    final_kernel<<<1, 64, 0, stream>>>(v, W2, b2, out);
}

// Round 3
// 342.985 us; speedup vs baseline: 1.7562x; 1.0981x over previous
//
#include <hip/hip_runtime.h>
#include <hip/hip_fp16.h>

#define NN 100000      // nodes
#define NE 1600000     // edges
#define INF 32
#define HF 32
#define CF 8

// ---------------- K1: degree histograms (int atomics) ----------------
__global__ void deg_kernel(const int* __restrict__ src, const int* __restrict__ dst,
                           int* __restrict__ deg_out, int* __restrict__ deg_in) {
    int e = blockIdx.x * blockDim.x + threadIdx.x;
    if (e < NE) {
        atomicAdd(&deg_out[src[e]], 1);
        atomicAdd(&deg_in[dst[e]], 1);
    }
}

// ---------------- K2: h = (x @ W1) * rsqrt(deg_out), stored as packed f16 pairs ----------------
__global__ void xw1_kernel(const float* __restrict__ x, const float* __restrict__ W1,
                           const int* __restrict__ deg_out, unsigned int* __restrict__ h) {
    __shared__ float w[INF * HF];
    for (int i = threadIdx.x; i < INF * HF; i += blockDim.x) w[i] = W1[i];
    __syncthreads();
    int n = blockIdx.x * blockDim.x + threadIdx.x;
    if (n >= NN) return;

    float xr[INF];
    const float4* xp = (const float4*)(x + (size_t)n * INF);
    #pragma unroll
    for (int i = 0; i < INF / 4; ++i) {
        float4 v = xp[i];
        xr[4*i+0] = v.x; xr[4*i+1] = v.y; xr[4*i+2] = v.z; xr[4*i+3] = v.w;
    }
    float acc[HF];
    #pragma unroll
    for (int c = 0; c < HF; ++c) acc[c] = 0.0f;
    #pragma unroll
    for (int k = 0; k < INF; ++k) {
        float xv = xr[k];
        #pragma unroll
        for (int c = 0; c < HF; ++c) acc[c] = fmaf(xv, w[k * HF + c], acc[c]);
    }
    float rs = rsqrtf(fmaxf((float)deg_out[n], 1.0f));

    // pack 32 f32 -> 16 uint (2xf16, RNE)
    unsigned int pk[HF / 2];
    #pragma unroll
    for (int i = 0; i < HF / 2; ++i) {
        __half2 p = __floats2half2_rn(acc[2*i] * rs, acc[2*i+1] * rs);
        pk[i] = *(unsigned int*)&p;
    }
    uint4* hp = (uint4*)(h + (size_t)n * (HF / 2));
    #pragma unroll
    for (int i = 0; i < 4; ++i) {
        uint4 v;
        v.x = pk[4*i+0]; v.y = pk[4*i+1]; v.z = pk[4*i+2]; v.w = pk[4*i+3];
        hp[i] = v;
    }
}

// ---------------- K3: agg1[dst] += h[src] via packed-f16 atomics; wgt[src] += rs_in[dst] ----------------
// 16 lanes per edge, each lane one pk atomic (2 features).
__global__ void __launch_bounds__(256) scatter_pk_kernel(
        const int* __restrict__ src, const int* __restrict__ dst,
        const int* __restrict__ deg_in,
        const unsigned int* __restrict__ h, unsigned int* __restrict__ agg,
        float* __restrict__ wgt) {
    long long t = (long long)blockIdx.x * blockDim.x + threadIdx.x;  // < NE*16
    int e = (int)(t >> 4);
    int lane = (int)(t & 15);
    if (e >= NE) return;
    int s = src[e], d = dst[e];
    unsigned int val = h[(size_t)s * 16 + lane];
    unsigned int* addr = agg + (size_t)d * 16 + lane;
    asm volatile("global_atomic_pk_add_f16 %0, %1, off"
                 :: "v"(addr), "v"(val) : "memory");
    if (lane == 0) {
        float riv = rsqrtf(fmaxf((float)deg_in[d], 1.0f));
        atomicAdd(&wgt[s], riv);
    }
}

// ---------------- K4: v[32] = sum_n (rs_out[n]*wgt[n]) * relu(agg1[n]*rs_in[n] + b1) ----------------
__global__ void __launch_bounds__(256) reduce_kernel(
        const unsigned int* __restrict__ agg,
        const int* __restrict__ deg_in, const int* __restrict__ deg_out,
        const float* __restrict__ wgt, const float* __restrict__ b1,
        float* __restrict__ v) {
    const int lane8 = threadIdx.x & 7;       // feature sub-group: owns 4 channels
    const int f0 = lane8 * 4;
    const int group = (blockIdx.x * blockDim.x + threadIdx.x) >> 3;
    const int ngroups = (gridDim.x * blockDim.x) >> 3;

    float b1r[4];
    #pragma unroll
    for (int c = 0; c < 4; ++c) b1r[c] = b1[f0 + c];

    float vacc[4] = {0.f, 0.f, 0.f, 0.f};

    for (int n = group; n < NN; n += ngroups) {
        // 2 uints = 4 f16 features for this lane's channel block
        uint2 a = *(const uint2*)(agg + (size_t)n * 16 + lane8 * 2);
        float2 lo = __half22float2(*(__half2*)&a.x);
        float2 hi = __half22float2(*(__half2*)&a.y);
        float rs_in  = rsqrtf(fmaxf((float)deg_in[n], 1.0f));
        float rs_out = rsqrtf(fmaxf((float)deg_out[n], 1.0f));
        float alpha = rs_out * wgt[n];
        vacc[0] += alpha * fmaxf(fmaf(lo.x, rs_in, b1r[0]), 0.f);
        vacc[1] += alpha * fmaxf(fmaf(lo.y, rs_in, b1r[1]), 0.f);
        vacc[2] += alpha * fmaxf(fmaf(hi.x, rs_in, b1r[2]), 0.f);
        vacc[3] += alpha * fmaxf(fmaf(hi.y, rs_in, b1r[3]), 0.f);
    }

    // reduce across the 8 node-groups within the wave (lanes differing in bits 3,4,5)
    #pragma unroll
    for (int c = 0; c < 4; ++c) {
        vacc[c] += __shfl_xor(vacc[c], 8, 64);
        vacc[c] += __shfl_xor(vacc[c], 16, 64);
        vacc[c] += __shfl_xor(vacc[c], 32, 64);
    }
    __shared__ float vl[32];
    if (threadIdx.x < 32) vl[threadIdx.x] = 0.f;
    __syncthreads();
    if ((threadIdx.x & 63) < 8) {
        #pragma unroll
        for (int c = 0; c < 4; ++c) atomicAdd(&vl[f0 + c], vacc[c]);
    }
    __syncthreads();
    if (threadIdx.x < 32) atomicAdd(&v[threadIdx.x], vl[threadIdx.x]);
}

// ---------------- K5: out = (v @ W2)/N + b2 ----------------
__global__ void final_kernel(const float* __restrict__ v, const float* __restrict__ W2,
                             const float* __restrict__ b2, float* __restrict__ out) {
    int c = threadIdx.x;
    if (c < CF) {
        float s = 0.f;
        #pragma unroll
        for (int k = 0; k < HF; ++k) s = fmaf(v[k], W2[k * CF + c], s);
        out[c] = s * (1.0f / NN) + b2[c];
    }
}

extern "C" void kernel_launch(void* const* d_in, const int* in_sizes, int n_in,
                              void* d_out, int out_size, void* d_ws, size_t ws_size,
                              hipStream_t stream) {
    const float* x   = (const float*)d_in[0];
    const int*   src = (const int*)  d_in[1];
    const int*   dst = (const int*)  d_in[2];
    const float* W1  = (const float*)d_in[3];
    const float* b1  = (const float*)d_in[4];
    const float* W2  = (const float*)d_in[5];
    const float* b2  = (const float*)d_in[6];
    float* out = (float*)d_out;

    char* ws = (char*)d_ws;
    int*          deg_out = (int*)ws;           ws += NN * 4;
    int*          deg_in  = (int*)ws;           ws += NN * 4;
    unsigned int* h       = (unsigned int*)ws;  ws += (size_t)NN * 16 * 4;  // f16 pairs
    unsigned int* agg1    = (unsigned int*)ws;  ws += (size_t)NN * 16 * 4;  // f16 pairs
    float*        wgt     = (float*)ws;         ws += NN * 4;
    float*        v       = (float*)ws;         ws += 32 * 4;

    // zero accumulators (deterministic per call)
    hipMemsetAsync(deg_out, 0, 2 * (size_t)NN * 4, stream);                       // deg
    hipMemsetAsync(agg1, 0, ((size_t)NN * 16 + NN + 32) * 4, stream);             // agg1+wgt+v

    const int B = 256;
    deg_kernel<<<(NE + B - 1) / B, B, 0, stream>>>(src, dst, deg_out, deg_in);
    xw1_kernel<<<(NN + B - 1) / B, B, 0, stream>>>(x, W1, deg_out, h);
    scatter_pk_kernel<<<(int)(((long long)NE * 16 + B - 1) / B), B, 0, stream>>>(
        src, dst, deg_in, h, agg1, wgt);
    reduce_kernel<<<2048, B, 0, stream>>>(agg1, deg_in, deg_out, wgt, b1, v);
    final_kernel<<<1, 64, 0, stream>>>(v, W2, b2, out);
}